// Round 7
// baseline (113.678 us; speedup 1.0000x reference)
//
#include <hip/hip_runtime.h>
#include <math.h>

// StructureLoss: B=32, C=1, H=W=512, 31x31 box filter, pad 15
#define BB 32
#define HH 512
#define WW 512
#define KK 31
#define PP 15

#define ASEG 64                        // rows per pass-A segment
#define A_NBLK (BB * (HH/ASEG) * 2)    // 32*8*2 = 512 blocks (256 cols each)

#define B_NBLK (BB * (HH/4))           // 4096 blocks, 4 rows (1/wave) each

__device__ inline float wave_reduce(float v) {
    #pragma unroll
    for (int off = 32; off > 0; off >>= 1) v += __shfl_down(v, off);
    return v;
}

// 3 transcendentals/px: e=exp(-|x|), r=rcp(1+e) -> sigmoid = r or 1-r,
// log1p(e) = -log(r)
__device__ inline void accum_px(float s, float tg, float x,
                                float& aw, float& ab, float& ai, float& au) {
    const float inv = 1.0f / (float)(KK * KK);
    float pooled = s * inv;
    float weit = fmaf(5.0f, fabsf(pooled - tg), 1.0f);
    float e  = __expf(-fabsf(x));
    float rr = __builtin_amdgcn_rcpf(1.0f + e);
    float bce = fmaxf(x, 0.0f) - x * tg - __logf(rr);
    float p  = (x >= 0.0f) ? rr : (1.0f - rr);
    aw += weit;
    ab = fmaf(weit, bce, ab);
    ai = fmaf(p * tg, weit, ai);
    au = fmaf(p + tg, weit, au);
}

// ---------------- Pass A: vertical 31-row box sum -> V in d_ws ----------------
__global__ __launch_bounds__(256) void vsum_kernel(
    const float* __restrict__ target, float* __restrict__ V)
{
    const int t   = threadIdx.x;
    const int blk = blockIdx.x;        // 512 = 32 img x 8 seg x 2 chunks
    const int b   = blk >> 4;
    const int seg = (blk >> 1) & 7;
    const int ch  = blk & 1;
    const int x   = ch * 256 + t;      // column (coalesced across wave)
    const int y0  = seg * ASEG;

    const float* tb = target + (size_t)b * HH * WW + x;
    float*       vb = V      + (size_t)b * HH * WW + x;

    float s = 0.f;
    if (seg > 0 && seg < 7) {          // interior: all accesses in-bounds
        #pragma unroll
        for (int j = -PP; j <= PP; ++j) s += tb[(y0 + j) * WW];
        #pragma unroll 16
        for (int r = 0; r < ASEG; ++r) {
            vb[(y0 + r) * WW] = s;
            s += tb[(y0 + r + PP + 1) * WW] - tb[(y0 + r - PP) * WW];
        }
    } else {
        #pragma unroll
        for (int j = -PP; j <= PP; ++j) {
            int y  = y0 + j;
            int yc = min(max(y, 0), HH - 1);
            float v = tb[yc * WW];
            s += (y >= 0 && y < HH) ? v : 0.f;
        }
        #pragma unroll 16
        for (int r = 0; r < ASEG; ++r) {
            vb[(y0 + r) * WW] = s;
            int ya = y0 + r + PP + 1;
            int ys = y0 + r - PP;
            float va = tb[min(ya, HH - 1) * WW];
            float vu = tb[max(ys, 0) * WW];
            s += ((ya < HH) ? va : 0.f) - ((ys >= 0) ? vu : 0.f);
        }
    }
}

// ------- Pass B: per-row horizontal 31-window via shuffles + loss accum -------
__device__ inline float4 ld4(const float* base, int c) {
    return *(const float4*)(base + c);
}

__global__ __launch_bounds__(256) void loss_kernel(
    const float* __restrict__ pred, const float* __restrict__ target,
    const float* __restrict__ V, float* __restrict__ partials /* [B_NBLK][4] */)
{
    __shared__ float red[4 * 4];

    const int t   = threadIdx.x;
    const int w   = t >> 6;            // wave 0..3 -> one row each
    const int L   = t & 63;
    const int blk = blockIdx.x;        // 4096
    const int b   = blk >> 7;          // image
    const int y   = (blk & 127) * 4 + w;
    const int c0  = 8 * L;             // lane owns cols [c0, c0+8)

    const float* rowV = V      + (size_t)b * HH * WW + (size_t)y * WW;
    const float* rowT = target + (size_t)b * HH * WW + (size_t)y * WW;
    const float* rowP = pred   + (size_t)b * HH * WW + (size_t)y * WW;

    // edge masks (exact zero padding at row ends)
    const float m_u1 = (L >= 1) ? 1.f : 0.f;
    const float m_u2 = (L >= 2) ? 1.f : 0.f;
    const float m_d1 = (L <= 62) ? 1.f : 0.f;
    const float m_d2 = (L <= 61) ? 1.f : 0.f;

    float4 vA = ld4(rowV, c0), vB = ld4(rowV, c0 + 4);
    float4 tA = ld4(rowT, c0), tB = ld4(rowT, c0 + 4);
    float4 pA = ld4(rowP, c0), pB = ld4(rowP, c0 + 4);

    // horizontal 31-window via cross-lane (verified in R6, absmax 0)
    float own  = vA.x + vA.y + vA.z + vA.w + vB.x + vB.y + vB.z + vB.w;
    float own7 = own - vA.x;
    float s0 = own
             + m_u2 * __shfl_up(own7, 2)
             + m_u1 * __shfl_up(own, 1)
             + m_d1 * __shfl_down(own, 1);
    float a0 = m_d2 * __shfl_down(vA.x, 2);
    float a1 = m_d2 * __shfl_down(vA.y, 2);
    float a2 = m_d2 * __shfl_down(vA.z, 2);
    float a3 = m_d2 * __shfl_down(vA.w, 2);
    float a4 = m_d2 * __shfl_down(vB.x, 2);
    float a5 = m_d2 * __shfl_down(vB.y, 2);
    float a6 = m_d2 * __shfl_down(vB.z, 2);
    float q0 = m_u2 * __shfl_up(vA.y, 2);
    float q1 = m_u2 * __shfl_up(vA.z, 2);
    float q2 = m_u2 * __shfl_up(vA.w, 2);
    float q3 = m_u2 * __shfl_up(vB.x, 2);
    float q4 = m_u2 * __shfl_up(vB.y, 2);
    float q5 = m_u2 * __shfl_up(vB.z, 2);
    float q6 = m_u2 * __shfl_up(vB.w, 2);

    float s1 = s0 + a0 - q0;
    float s2 = s1 + a1 - q1;
    float s3 = s2 + a2 - q2;
    float s4 = s3 + a3 - q3;
    float s5 = s4 + a4 - q4;
    float s6 = s5 + a5 - q5;
    float s7 = s6 + a6 - q6;

    float aw = 0.f, ab = 0.f, ai = 0.f, au = 0.f;
    accum_px(s0, tA.x, pA.x, aw, ab, ai, au);
    accum_px(s1, tA.y, pA.y, aw, ab, ai, au);
    accum_px(s2, tA.z, pA.z, aw, ab, ai, au);
    accum_px(s3, tA.w, pA.w, aw, ab, ai, au);
    accum_px(s4, tB.x, pB.x, aw, ab, ai, au);
    accum_px(s5, tB.y, pB.y, aw, ab, ai, au);
    accum_px(s6, tB.z, pB.z, aw, ab, ai, au);
    accum_px(s7, tB.w, pB.w, aw, ab, ai, au);

    aw = wave_reduce(aw);
    ab = wave_reduce(ab);
    ai = wave_reduce(ai);
    au = wave_reduce(au);
    if (L == 0) {
        red[w * 4 + 0] = aw;
        red[w * 4 + 1] = ab;
        red[w * 4 + 2] = ai;
        red[w * 4 + 3] = au;
    }
    __syncthreads();
    if (t == 0) {
        float ww = 0.f, bc = 0.f, in = 0.f, un = 0.f;
        #pragma unroll
        for (int i = 0; i < 4; ++i) {
            ww += red[i * 4 + 0];
            bc += red[i * 4 + 1];
            in += red[i * 4 + 2];
            un += red[i * 4 + 3];
        }
        float* o = partials + (size_t)blk * 4;
        o[0] = ww; o[1] = bc; o[2] = in; o[3] = un;
    }
}

// ------------------------------- finalize ------------------------------------
__global__ __launch_bounds__(256) void structure_loss_finalize(
    const float* __restrict__ partials, float* __restrict__ out)
{
    // partials: [4096][4]; image b owns entries [b*128, (b+1)*128)
    const int t  = threadIdx.x;      // 256 threads
    const int b  = t >> 3;           // image 0..31  (8 threads per image)
    const int i0 = (t & 7) * 16;     // 16 partial-entries per thread
    float w = 0.f, bc = 0.f, in = 0.f, un = 0.f;
    #pragma unroll
    for (int k = 0; k < 16; ++k) {
        float4 v = *(const float4*)(partials + ((size_t)(b * 128 + i0 + k)) * 4);
        w += v.x; bc += v.y; in += v.z; un += v.w;
    }
    #pragma unroll
    for (int off = 4; off > 0; off >>= 1) {
        w  += __shfl_down(w, off);
        bc += __shfl_down(bc, off);
        in += __shfl_down(in, off);
        un += __shfl_down(un, off);
    }
    __shared__ float vals[32];
    if ((t & 7) == 0) {
        float wbce = bc / w;
        float wiou = 1.0f - (in + 1.0f) / (un - in + 1.0f);
        vals[b] = wbce + wiou;
    }
    __syncthreads();
    if (t < 64) {
        float v = (t < 32) ? vals[t] : 0.0f;
        v = wave_reduce(v);
        if (t == 0) out[0] = v / (float)BB;
    }
}

extern "C" void kernel_launch(void* const* d_in, const int* in_sizes, int n_in,
                              void* d_out, int out_size, void* d_ws, size_t ws_size,
                              hipStream_t stream) {
    const float* pred   = (const float*)d_in[0];
    const float* target = (const float*)d_in[1];
    float* out = (float*)d_out;

    float* V        = (float*)d_ws;                          // 33.55 MB
    float* partials = (float*)((char*)d_ws + (size_t)BB * HH * WW * 4); // 64 KB

    vsum_kernel<<<A_NBLK, 256, 0, stream>>>(target, V);
    loss_kernel<<<B_NBLK, 256, 0, stream>>>(pred, target, V, partials);
    structure_loss_finalize<<<1, 256, 0, stream>>>(partials, out);
}

// Round 8
// 112.330 us; speedup vs baseline: 1.0120x; 1.0120x over previous
//
#include <hip/hip_runtime.h>
#include <math.h>

// StructureLoss: B=32, C=1, H=W=512, 31x31 box filter, pad 15
#define BB 32
#define HH 512
#define WW 512
#define KK 31
#define PP 15
#define WROWS 8                       // rows per wave (init amortized over 8)
#define HSEG 32                       // rows per block (4 waves x 8 rows)
#define BLOCKS_PER_IMG (HH / HSEG)    // 16
#define NBLOCKS (BB * BLOCKS_PER_IMG) // 512 -> 2 blocks/CU, 8 waves/CU
#define NTHREADS 256

__device__ inline float wave_reduce(float v) {
    #pragma unroll
    for (int off = 32; off > 0; off >>= 1) v += __shfl_down(v, off);
    return v;
}

// 3 transcendentals/px: e=exp(-|x|), r=rcp(1+e) -> sigmoid = r or 1-r,
// log1p(e) = -log(r)
__device__ inline void accum_px(float s, float tg, float x,
                                float& aw, float& ab, float& ai, float& au) {
    const float inv = 1.0f / (float)(KK * KK);
    float pooled = s * inv;
    float weit = fmaf(5.0f, fabsf(pooled - tg), 1.0f);
    float e  = __expf(-fabsf(x));
    float rr = __builtin_amdgcn_rcpf(1.0f + e);
    float bce = fmaxf(x, 0.0f) - x * tg - __logf(rr);
    float p  = (x >= 0.0f) ? rr : (1.0f - rr);
    aw += weit;
    ab = fmaf(weit, bce, ab);
    ai = fmaf(p * tg, weit, ai);
    au = fmaf(p + tg, weit, au);
}

__device__ inline float4 ld4(const float* base, int y, int c) {
    return *(const float4*)(base + (size_t)y * WW + c);
}
// row-clamped load, zeroed if row OOB (y is wave-uniform)
__device__ inline float4 ld4z(const float* base, int y, int c) {
    int yc = min(max(y, 0), HH - 1);
    float4 v = *(const float4*)(base + (size_t)yc * WW + c);
    if (y < 0 || y >= HH) v = make_float4(0.f, 0.f, 0.f, 0.f);
    return v;
}

__global__ __launch_bounds__(NTHREADS, 2) void structure_loss_main(
    const float* __restrict__ pred, const float* __restrict__ target,
    float* __restrict__ partials /* [NBLOCKS][4] */)
{
    __shared__ float red[4 * 4];

    const int t   = threadIdx.x;
    const int w   = t >> 6;            // wave 0..3
    const int L   = t & 63;            // lane
    const int blk = blockIdx.x;
    const int b   = blk >> 4;          // image
    const int seg = blk & 15;          // 32-row segment
    const int y0  = seg * HSEG + w * WROWS;   // wave's first row
    const int c0  = 8 * L;             // lane owns cols [c0, c0+8)

    const float* tb = target + (size_t)b * HH * WW;
    const float* pb = pred   + (size_t)b * HH * WW;

    // edge masks for cross-lane halo (exact zero padding at row ends)
    const float m_u1 = (L >= 1) ? 1.f : 0.f;
    const float m_u2 = (L >= 2) ? 1.f : 0.f;
    const float m_d1 = (L <= 62) ? 1.f : 0.f;
    const float m_d2 = (L <= 61) ? 1.f : 0.f;

    // ---- vertical running sums for rows [y0-15, y0+15], 8 cols in regs ----
    float4 vsA = make_float4(0.f,0.f,0.f,0.f);
    float4 vsB = make_float4(0.f,0.f,0.f,0.f);
    if (y0 >= PP && y0 + PP < HH) {            // interior (wave-uniform branch)
        #pragma unroll
        for (int j = -PP; j <= PP; ++j) {
            float4 u = ld4(tb, y0 + j, c0);
            float4 v = ld4(tb, y0 + j, c0 + 4);
            vsA.x += u.x; vsA.y += u.y; vsA.z += u.z; vsA.w += u.w;
            vsB.x += v.x; vsB.y += v.y; vsB.z += v.z; vsB.w += v.w;
        }
    } else {
        #pragma unroll
        for (int j = -PP; j <= PP; ++j) {
            float4 u = ld4z(tb, y0 + j, c0);
            float4 v = ld4z(tb, y0 + j, c0 + 4);
            vsA.x += u.x; vsA.y += u.y; vsA.z += u.z; vsA.w += u.w;
            vsB.x += v.x; vsB.y += v.y; vsB.z += v.z; vsB.w += v.w;
        }
    }

    // prologue prefetch for row y0
    float4 tgA = ld4(tb, y0, c0),  tgB = ld4(tb, y0, c0 + 4);
    float4 prA = ld4(pb, y0, c0),  prB = ld4(pb, y0, c0 + 4);
    float4 adA = ld4z(tb, y0 + PP + 1, c0), adB = ld4z(tb, y0 + PP + 1, c0 + 4);
    float4 sbA = ld4z(tb, y0 - PP, c0),     sbB = ld4z(tb, y0 - PP, c0 + 4);

    float aw = 0.f, ab = 0.f, ai = 0.f, au = 0.f;

    #pragma unroll
    for (int r = 0; r < WROWS; ++r) {
        // prefetch next row (in flight across this row's compute; no barriers)
        float4 tgA2, tgB2, prA2, prB2, adA2, adB2, sbA2, sbB2;
        if (r < WROWS - 1) {
            int y = y0 + r + 1;
            tgA2 = ld4(tb, y, c0);  tgB2 = ld4(tb, y, c0 + 4);
            prA2 = ld4(pb, y, c0);  prB2 = ld4(pb, y, c0 + 4);
            adA2 = ld4z(tb, y + PP + 1, c0); adB2 = ld4z(tb, y + PP + 1, c0 + 4);
            sbA2 = ld4z(tb, y - PP, c0);     sbB2 = ld4z(tb, y - PP, c0 + 4);
        }

        // ---- horizontal 31-window via cross-lane (17 shuffles, no LDS) ----
        float own  = vsA.x + vsA.y + vsA.z + vsA.w + vsB.x + vsB.y + vsB.z + vsB.w;
        float own7 = own - vsA.x;   // neighbor's cols 1..7 when shifted
        // s(c0) = sum cols [c0-15, c0+15]
        float s0 = own
                 + m_u2 * __shfl_up(own7, 2)
                 + m_u1 * __shfl_up(own, 1)
                 + m_d1 * __shfl_down(own, 1);
        // add taps: cols c0+16..c0+22 = lane L+2 elems 0..6
        float a0 = m_d2 * __shfl_down(vsA.x, 2);
        float a1 = m_d2 * __shfl_down(vsA.y, 2);
        float a2 = m_d2 * __shfl_down(vsA.z, 2);
        float a3 = m_d2 * __shfl_down(vsA.w, 2);
        float a4 = m_d2 * __shfl_down(vsB.x, 2);
        float a5 = m_d2 * __shfl_down(vsB.y, 2);
        float a6 = m_d2 * __shfl_down(vsB.z, 2);
        // sub taps: cols c0-15..c0-9 = lane L-2 elems 1..7
        float q0 = m_u2 * __shfl_up(vsA.y, 2);
        float q1 = m_u2 * __shfl_up(vsA.z, 2);
        float q2 = m_u2 * __shfl_up(vsA.w, 2);
        float q3 = m_u2 * __shfl_up(vsB.x, 2);
        float q4 = m_u2 * __shfl_up(vsB.y, 2);
        float q5 = m_u2 * __shfl_up(vsB.z, 2);
        float q6 = m_u2 * __shfl_up(vsB.w, 2);

        float s1 = s0 + a0 - q0;
        float s2 = s1 + a1 - q1;
        float s3 = s2 + a2 - q2;
        float s4 = s3 + a3 - q3;
        float s5 = s4 + a4 - q4;
        float s6 = s5 + a5 - q5;
        float s7 = s6 + a6 - q6;

        accum_px(s0, tgA.x, prA.x, aw, ab, ai, au);
        accum_px(s1, tgA.y, prA.y, aw, ab, ai, au);
        accum_px(s2, tgA.z, prA.z, aw, ab, ai, au);
        accum_px(s3, tgA.w, prA.w, aw, ab, ai, au);
        accum_px(s4, tgB.x, prB.x, aw, ab, ai, au);
        accum_px(s5, tgB.y, prB.y, aw, ab, ai, au);
        accum_px(s6, tgB.z, prB.z, aw, ab, ai, au);
        accum_px(s7, tgB.w, prB.w, aw, ab, ai, au);

        // vertical slide to next row
        vsA.x += adA.x - sbA.x; vsA.y += adA.y - sbA.y;
        vsA.z += adA.z - sbA.z; vsA.w += adA.w - sbA.w;
        vsB.x += adB.x - sbB.x; vsB.y += adB.y - sbB.y;
        vsB.z += adB.z - sbB.z; vsB.w += adB.w - sbB.w;

        tgA = tgA2; tgB = tgB2; prA = prA2; prB = prB2;
        adA = adA2; adB = adB2; sbA = sbA2; sbB = sbB2;
    }

    // block reduction (the only barriers in the kernel, at the very end)
    aw = wave_reduce(aw);
    ab = wave_reduce(ab);
    ai = wave_reduce(ai);
    au = wave_reduce(au);
    if (L == 0) {
        red[w * 4 + 0] = aw;
        red[w * 4 + 1] = ab;
        red[w * 4 + 2] = ai;
        red[w * 4 + 3] = au;
    }
    __syncthreads();
    if (t == 0) {
        float ww = 0.f, bc = 0.f, in = 0.f, un = 0.f;
        #pragma unroll
        for (int i = 0; i < 4; ++i) {
            ww += red[i * 4 + 0];
            bc += red[i * 4 + 1];
            in += red[i * 4 + 2];
            un += red[i * 4 + 3];
        }
        float* o = partials + (size_t)blk * 4;
        o[0] = ww; o[1] = bc; o[2] = in; o[3] = un;
    }
}

__global__ __launch_bounds__(256) void structure_loss_finalize(
    const float* __restrict__ partials, float* __restrict__ out)
{
    // partials: [512][4]; image b owns entries [b*16, (b+1)*16)
    const int t  = threadIdx.x;      // 256 threads
    const int b  = t >> 3;           // image 0..31  (8 threads per image)
    const int i0 = (t & 7) * 2;      // 2 partial-entries per thread
    float w = 0.f, bc = 0.f, in = 0.f, un = 0.f;
    #pragma unroll
    for (int k = 0; k < 2; ++k) {
        float4 v = *(const float4*)(partials + ((size_t)(b * 16 + i0 + k)) * 4);
        w += v.x; bc += v.y; in += v.z; un += v.w;
    }
    #pragma unroll
    for (int off = 4; off > 0; off >>= 1) {
        w  += __shfl_down(w, off);
        bc += __shfl_down(bc, off);
        in += __shfl_down(in, off);
        un += __shfl_down(un, off);
    }
    __shared__ float vals[32];
    if ((t & 7) == 0) {
        float wbce = bc / w;
        float wiou = 1.0f - (in + 1.0f) / (un - in + 1.0f);
        vals[b] = wbce + wiou;
    }
    __syncthreads();
    if (t < 64) {
        float v = (t < 32) ? vals[t] : 0.0f;
        v = wave_reduce(v);
        if (t == 0) out[0] = v / (float)BB;
    }
}

extern "C" void kernel_launch(void* const* d_in, const int* in_sizes, int n_in,
                              void* d_out, int out_size, void* d_ws, size_t ws_size,
                              hipStream_t stream) {
    const float* pred   = (const float*)d_in[0];
    const float* target = (const float*)d_in[1];
    float* out      = (float*)d_out;
    float* partials = (float*)d_ws;   // NBLOCKS*4 floats = 8 KB

    structure_loss_main<<<NBLOCKS, NTHREADS, 0, stream>>>(pred, target, partials);
    structure_loss_finalize<<<1, 256, 0, stream>>>(partials, out);
}